// Round 3
// baseline (134.871 us; speedup 1.0000x reference)
//
#include <hip/hip_runtime.h>

// Problem constants (from reference)
#define BB   4
#define N1   1024
#define DIM  1024
#define FF   4
#define NN   1025           // N1 + 1
#define NTOT (FF * NN)      // 4100
#define SIM_TOTAL ((size_t)BB * N1 * NTOT)   // 16,793,600 floats (divisible by 4)
#define NEGV (-1e9f)

// ---------------------------------------------------------------------------
// Kernel 1: pure streaming fill of the sim region with -1e9.
// ---------------------------------------------------------------------------
__global__ __launch_bounds__(256)
void fill_kernel(float4* __restrict__ out4, int total4) {
    const float4 negv = make_float4(NEGV, NEGV, NEGV, NEGV);
    const int stride = gridDim.x * 256;
    for (int k = blockIdx.x * 256 + threadIdx.x; k < total4; k += stride)
        out4[k] = negv;
}

// ---------------------------------------------------------------------------
// Kernel 2: one block per row (b,i); wave f handles frame f.
//   Each wave: 4 float4/lane of lhs + 4 float4/lane of rhs row f*NN+i+1
//   (8 independent loads in flight, ~32 data VGPRs), butterfly-reduce
//   l2 / dot / r2 within the wave, lane 0 writes sim; wave 0 writes norm.
//   No LDS, no __syncthreads. lhs row redundantly read by 4 waves -> L2 hits.
// ---------------------------------------------------------------------------
__global__ __launch_bounds__(256)
void dot_kernel(const float* __restrict__ lhs,
                const float* __restrict__ rhs,
                float* __restrict__ out) {
    const int row  = blockIdx.x;          // 0 .. B*N1-1
    const int f    = threadIdx.x >> 6;    // wave id = frame index
    const int lane = threadIdx.x & 63;
    const int b    = row >> 10;           // / N1
    const int i    = row & (N1 - 1);      // % N1

    const float4* lrow = (const float4*)(lhs + (size_t)row * DIM);
    const float4* rrow = (const float4*)(rhs +
        ((size_t)b * NTOT + (size_t)f * NN + (i + 1)) * DIM);

    float4 lv[4], rv[4];
#pragma unroll
    for (int k = 0; k < 4; ++k) lv[k] = lrow[lane + 64 * k];
#pragma unroll
    for (int k = 0; k < 4; ++k) rv[k] = rrow[lane + 64 * k];

    float l2 = 0.f, d = 0.f, r2 = 0.f;
#pragma unroll
    for (int k = 0; k < 4; ++k) {
        l2 += lv[k].x * lv[k].x + lv[k].y * lv[k].y +
              lv[k].z * lv[k].z + lv[k].w * lv[k].w;
        d  += lv[k].x * rv[k].x + lv[k].y * rv[k].y +
              lv[k].z * rv[k].z + lv[k].w * rv[k].w;
        r2 += rv[k].x * rv[k].x + rv[k].y * rv[k].y +
              rv[k].z * rv[k].z + rv[k].w * rv[k].w;
    }

    // butterfly reduce 3 scalars across the 64-lane wave
#pragma unroll
    for (int off = 1; off < 64; off <<= 1) {
        l2 += __shfl_xor(l2, off, 64);
        d  += __shfl_xor(d,  off, 64);
        r2 += __shfl_xor(r2, off, 64);
    }

    if (lane == 0) {
        out[(size_t)row * NTOT + (size_t)f * NN + (i + 1)] = (d * d) / (l2 * r2);
        if (f == 0)
            out[SIM_TOTAL + row] = sqrtf(l2);   // lhs_norm (B, N1, 1)
    }
}

extern "C" void kernel_launch(void* const* d_in, const int* in_sizes, int n_in,
                              void* d_out, int out_size, void* d_ws, size_t ws_size,
                              hipStream_t stream) {
    const float* lhs = (const float*)d_in[0];  // (B, N1, DIM)
    const float* rhs = (const float*)d_in[1];  // (B, NTOT, DIM)
    float* out = (float*)d_out;                // sim (B,N1,NTOT) ++ lhs_norm (B,N1,1)

    const int total4 = (int)(SIM_TOTAL / 4);   // 4,198,400 float4
    fill_kernel<<<2048, 256, 0, stream>>>((float4*)out, total4);
    dot_kernel<<<BB * N1, 256, 0, stream>>>(lhs, rhs, out);
}

// Round 5
// 129.574 us; speedup vs baseline: 1.0409x; 1.0409x over previous
//
#include <hip/hip_runtime.h>

// Problem constants (from reference)
#define BB   4
#define N1   1024
#define DIM  1024
#define FF   4
#define NN   1025           // N1 + 1
#define NTOT (FF * NN)      // 4100
#define SIM_TOTAL ((size_t)BB * N1 * NTOT)   // 16,793,600 floats
#define NEGV (-1e9f)

typedef float vfloat4 __attribute__((ext_vector_type(4)));   // native vec for nontemporal builtin

// ---------------------------------------------------------------------------
// Single fused kernel: one WAVE per row (b,i). No LDS, no barriers, 1 launch.
//   * 20 independent float4 loads/lane (4 lhs + 16 rhs) -> max MLP
//   * butterfly-reduce l2, dot[4], r2[4] across the 64-lane wave
//   * every lane streams its share of the row's 1025 float4 outputs,
//     patching the 4 kept sim values in-register (no store-then-patch,
//     no cross-lane ordering hazard), via non-temporal stores
//   * lane 0 writes lhs_norm
// ---------------------------------------------------------------------------
__global__ __launch_bounds__(256)
void lcs_kernel(const float* __restrict__ lhs,
                const float* __restrict__ rhs,
                float* __restrict__ out) {
    const int row  = blockIdx.x * 4 + (threadIdx.x >> 6);  // 0 .. B*N1-1
    const int lane = threadIdx.x & 63;
    const int b    = row >> 10;          // / N1
    const int i    = row & (N1 - 1);     // % N1

    // ---- loads: lhs row (4 float4/lane) + 4 rhs rows (4 float4/lane each) ----
    const float4* lrow = (const float4*)(lhs + (size_t)row * DIM);
    float4 lv[4];
#pragma unroll
    for (int k = 0; k < 4; ++k)
        lv[k] = lrow[lane + 64 * k];

    float4 rv[FF][4];
#pragma unroll
    for (int f = 0; f < FF; ++f) {
        const float4* rrow = (const float4*)(rhs +
            ((size_t)b * NTOT + (size_t)f * NN + (i + 1)) * DIM);
#pragma unroll
        for (int k = 0; k < 4; ++k)
            rv[f][k] = rrow[lane + 64 * k];
    }

    // ---- per-lane partials ----
    float l2 = 0.f;
#pragma unroll
    for (int k = 0; k < 4; ++k)
        l2 += lv[k].x * lv[k].x + lv[k].y * lv[k].y +
              lv[k].z * lv[k].z + lv[k].w * lv[k].w;

    float dotf[FF], r2f[FF];
#pragma unroll
    for (int f = 0; f < FF; ++f) {
        float d = 0.f, r2 = 0.f;
#pragma unroll
        for (int k = 0; k < 4; ++k) {
            d  += lv[k].x * rv[f][k].x + lv[k].y * rv[f][k].y +
                  lv[k].z * rv[f][k].z + lv[k].w * rv[f][k].w;
            r2 += rv[f][k].x * rv[f][k].x + rv[f][k].y * rv[f][k].y +
                  rv[f][k].z * rv[f][k].z + rv[f][k].w * rv[f][k].w;
        }
        dotf[f] = d;
        r2f[f]  = r2;
    }

    // ---- butterfly reduce 9 scalars; all lanes end with the totals ----
#pragma unroll
    for (int off = 1; off < 64; off <<= 1) {
        l2 += __shfl_xor(l2, off, 64);
#pragma unroll
        for (int f = 0; f < FF; ++f) {
            dotf[f] += __shfl_xor(dotf[f], off, 64);
            r2f[f]  += __shfl_xor(r2f[f],  off, 64);
        }
    }

    // ---- sims + their positions within the row ----
    float sim[FF];
    int   q[FF];
#pragma unroll
    for (int f = 0; f < FF; ++f) {
        sim[f] = (dotf[f] * dotf[f]) / (l2 * r2f[f]);
        q[f]   = f * NN + (i + 1);       // kept column within this row
    }

    // ---- stream the row: 1025 float4, fill -1e9 with in-register patch ----
    vfloat4* orow4 = (vfloat4*)(out + (size_t)row * NTOT);   // row*16400B, 16B-aligned
    for (int k = lane; k <= 1024; k += 64) {                 // lane 0 takes k=1024
        const int g = 4 * k;
        float v0 = NEGV, v1 = NEGV, v2 = NEGV, v3 = NEGV;
#pragma unroll
        for (int f = 0; f < FF; ++f) {
            v0 = (g + 0 == q[f]) ? sim[f] : v0;
            v1 = (g + 1 == q[f]) ? sim[f] : v1;
            v2 = (g + 2 == q[f]) ? sim[f] : v2;
            v3 = (g + 3 == q[f]) ? sim[f] : v3;
        }
        vfloat4 v;
        v.x = v0; v.y = v1; v.z = v2; v.w = v3;
        __builtin_nontemporal_store(v, &orow4[k]);
    }

    if (lane == 0)
        out[SIM_TOTAL + row] = sqrtf(l2);   // lhs_norm (B, N1, 1)
}

extern "C" void kernel_launch(void* const* d_in, const int* in_sizes, int n_in,
                              void* d_out, int out_size, void* d_ws, size_t ws_size,
                              hipStream_t stream) {
    const float* lhs = (const float*)d_in[0];  // (B, N1, DIM)
    const float* rhs = (const float*)d_in[1];  // (B, NTOT, DIM)
    float* out = (float*)d_out;                // sim (B,N1,NTOT) ++ lhs_norm (B,N1,1)

    lcs_kernel<<<(BB * N1) / 4, 256, 0, stream>>>(lhs, rhs, out);
}